// Round 1
// 4833.202 us; speedup vs baseline: 1.0569x; 1.0569x over previous
//
#include <hip/hip_runtime.h>

// LSTM T=256, N=128, D=H=1024, L=2.  Persistent cooperative kernel, 256 WGs x 512.
// WG (layer l, slice s) owns hidden units [8s,8s+8) => 32 gate cols, weights in LDS.
// Round-5 changes vs round-4:
//  (1) Distributed per-WG flags (16-B stride in the 4 KB bar buffer) replace the
//      single atomic counter per layer: producers do ONE relaxed agent store, the
//      consumers poll 128 flags in parallel (tid<128 spin each on one flag, then
//      __syncthreads).  No RMW serialization, no single hot LLC line.
//  (2) Register-preloaded K-loops: all 32 per-lane A-fragments (128 VGPRs) of a
//      512-half K-slice are loaded before the MFMA chain; layer-1 interleaves the
//      two dependent phases (own h1 recurrence + l0 output) so >=8 LLC loads stay
//      in flight throughout.  Old kloop was ~4-6 loads in flight (VGPR_Count 88).
// h exchange unchanged: time-unique slots, agent (sc1) stores staged through LDS,
// consumers use plain cached loads.  c-state in registers.  glds stride 36.

typedef _Float16 f16;
typedef f16  v8f16 __attribute__((ext_vector_type(8)));
typedef float v4f32 __attribute__((ext_vector_type(4)));

#define TSTEPS 256
#define SLOT   131072u
static constexpr size_t HS_BANK = (size_t)258 * SLOT;   // elems per layer bank

#define SZ_W     ((size_t)2*4096*2048*2)   /* fp16 weights [l][col][k2048] */
#define SZ_B     ((size_t)2*4096*4)        /* fused bias fp32 */
#define SZ_HSEQ  ((size_t)2*258*SLOT*2)    /* h slots, 2 banks, fp16 */
#define SZ_BAR   ((size_t)4096)            /* 2 layers x 128 flags x 16 B */
#define SZ_XF    ((size_t)256*128*1024*2)  /* x in fp16 */
#define NEED1    (SZ_W + SZ_B + SZ_HSEQ + SZ_BAR)
#define NEED2    (NEED1 + SZ_XF)

__global__ void lstm_init(const float* __restrict__ x,
                          const float* __restrict__ h0,
                          const float* __restrict__ Wih, const float* __restrict__ Whh,
                          const float* __restrict__ bih, const float* __restrict__ bhh,
                          f16* __restrict__ wsW, float* __restrict__ wsB,
                          f16* __restrict__ hseq, unsigned* __restrict__ bar,
                          f16* __restrict__ xf, int do_xf)
{
    size_t tid  = (size_t)blockIdx.x * blockDim.x + threadIdx.x;
    size_t nthr = (size_t)gridDim.x * blockDim.x;
    // weights: [l][col][k], k<1024 -> W_ih, k>=1024 -> W_hh
    for (size_t i = tid; i < 16777216u; i += nthr) {
        unsigned l = (unsigned)(i >> 23), rem = (unsigned)(i & 8388607u);
        unsigned col = rem >> 11, k = rem & 2047u;
        float v = (k < 1024u) ? Wih[(size_t)l*4194304u + (size_t)col*1024u + k]
                              : Whh[(size_t)l*4194304u + (size_t)col*1024u + (k-1024u)];
        wsW[i] = (f16)v;
    }
    for (size_t i = tid; i < 8192u; i += nthr) wsB[i] = bih[i] + bhh[i];
    for (size_t i = tid; i < 131072u; i += nthr) {
        hseq[i]           = (f16)h0[i];             // layer0 slot 0
        hseq[HS_BANK + i] = (f16)h0[131072u + i];   // layer1 slot 0
    }
    for (size_t i = tid; i < 1024u; i += nthr) bar[i] = 0u;   // all flags
    if (do_xf) {
        for (size_t i = tid; i < 33554432u; i += nthr) xf[i] = (f16)x[i];
    }
}

__device__ __forceinline__ float sigmoid_fast(float v) { return 1.0f / (1.0f + __expf(-v)); }
__device__ __forceinline__ float tanh_fast(float v)    { return 1.0f - 2.0f / (__expf(2.0f*v) + 1.0f); }

__device__ __forceinline__ v8f16 cvt8(v4f32 lo, v4f32 hi) {
    v8f16 r;
    r[0]=(f16)lo[0]; r[1]=(f16)lo[1]; r[2]=(f16)lo[2]; r[3]=(f16)lo[3];
    r[4]=(f16)hi[0]; r[5]=(f16)hi[1]; r[6]=(f16)hi[2]; r[7]=(f16)hi[3];
    return r;
}

__device__ __forceinline__ unsigned ld_cnt(const unsigned* p) {
    return __hip_atomic_load(p, __ATOMIC_RELAXED, __HIP_MEMORY_SCOPE_AGENT);
}

#define CHUNK 8

// load 8 K-iterations' A-fragments (2 rows x 16 B each) into registers
__device__ __forceinline__ void load_chunk(const f16* p0, const f16* p1, int off,
                                           v8f16 a0[CHUNK], v8f16 a1[CHUNK])
{
    #pragma unroll
    for (int i = 0; i < CHUNK; ++i) {
        a0[i] = *(const v8f16*)(p0 + off + 32*i);
        a1[i] = *(const v8f16*)(p1 + off + 32*i);
    }
}

// consume one 8-iteration chunk (B from LDS weights)
__device__ __forceinline__ void mfma_chunk(const v8f16 a0[CHUNK], const v8f16 a1[CHUNK],
                                           const f16 (*wl)[2056], int l15, int kq, int kbase,
                                           v4f32 acc[2][2])
{
    #pragma unroll
    for (int i = 0; i < CHUNK; ++i) {
        int k = kbase + 32*i;
        v8f16 b0 = *(const v8f16*)(&wl[l15     ][k + kq]);
        v8f16 b1 = *(const v8f16*)(&wl[16 + l15][k + kq]);
        acc[0][0] = __builtin_amdgcn_mfma_f32_16x16x32_f16(a0[i], b0, acc[0][0], 0, 0, 0);
        acc[0][1] = __builtin_amdgcn_mfma_f32_16x16x32_f16(a0[i], b1, acc[0][1], 0, 0, 0);
        acc[1][0] = __builtin_amdgcn_mfma_f32_16x16x32_f16(a1[i], b0, acc[1][0], 0, 0, 0);
        acc[1][1] = __builtin_amdgcn_mfma_f32_16x16x32_f16(a1[i], b1, acc[1][1], 0, 0, 0);
    }
}

// legacy 16-iteration K-loop (kept for the fp32-x fallback path only)
__device__ __forceinline__ void kloop16(const f16* p0, const f16* p1,
                                        const f16 (*wl)[2056], int l15, int kq, int kofs,
                                        v4f32 acc[2][2])
{
    #pragma unroll
    for (int k = 0; k < 512; k += 32) {
        v8f16 a0 = *(const v8f16*)(p0 + k);
        v8f16 a1 = *(const v8f16*)(p1 + k);
        v8f16 b0 = *(const v8f16*)(&wl[l15     ][kofs + k + kq]);
        v8f16 b1 = *(const v8f16*)(&wl[16 + l15][kofs + k + kq]);
        acc[0][0] = __builtin_amdgcn_mfma_f32_16x16x32_f16(a0, b0, acc[0][0], 0, 0, 0);
        acc[0][1] = __builtin_amdgcn_mfma_f32_16x16x32_f16(a0, b1, acc[0][1], 0, 0, 0);
        acc[1][0] = __builtin_amdgcn_mfma_f32_16x16x32_f16(a1, b0, acc[1][0], 0, 0, 0);
        acc[1][1] = __builtin_amdgcn_mfma_f32_16x16x32_f16(a1, b1, acc[1][1], 0, 0, 0);
    }
}

__device__ __forceinline__ void reduce_splits(v4f32 acc[2][2], float (*gl)[36],
                                              int rb, int quad, int l15, int ks)
{
    if (ks == 0) {
        #pragma unroll
        for (int mt = 0; mt < 2; ++mt) {
            int rrow = (rb << 5) + (mt << 4) + (quad << 2);
            #pragma unroll
            for (int r = 0; r < 4; ++r) {
                gl[rrow + r][l15     ] = acc[mt][0][r];
                gl[rrow + r][16 + l15] = acc[mt][1][r];
            }
        }
    }
    __syncthreads();
    if (ks == 1) {
        #pragma unroll
        for (int mt = 0; mt < 2; ++mt) {
            int rrow = (rb << 5) + (mt << 4) + (quad << 2);
            #pragma unroll
            for (int r = 0; r < 4; ++r) {
                gl[rrow + r][l15     ] += acc[mt][0][r];
                gl[rrow + r][16 + l15] += acc[mt][1][r];
            }
        }
    }
    __syncthreads();
}

__device__ __forceinline__ void cell2(const float (*gl)[36], int n1, int u,
                                      float bi, float bf, float bg, float bo,
                                      float& cr0, float& cr1, float& h0o, float& h1o)
{
    {
        float gi = gl[n1][u]      + bi;
        float gf = gl[n1][8 + u]  + bf;
        float gg = gl[n1][16 + u] + bg;
        float go = gl[n1][24 + u] + bo;
        float cn = sigmoid_fast(gf) * cr0 + sigmoid_fast(gi) * tanh_fast(gg);
        cr0 = cn;
        h0o = sigmoid_fast(go) * tanh_fast(cn);
    }
    {
        int n = n1 + 64;
        float gi = gl[n][u]      + bi;
        float gf = gl[n][8 + u]  + bf;
        float gg = gl[n][16 + u] + bg;
        float go = gl[n][24 + u] + bo;
        float cn = sigmoid_fast(gf) * cr1 + sigmoid_fast(gi) * tanh_fast(gg);
        cr1 = cn;
        h1o = sigmoid_fast(go) * tanh_fast(cn);
    }
}

// stage hv values in LDS, then 128 threads store 16 B each (two 8-B agent stores)
__device__ __forceinline__ void store_h_slot(f16 (*hst)[8], f16* slotbase, int s,
                                             int tid, int n1, int u,
                                             float hv0, float hv1)
{
    hst[n1     ][u] = (f16)hv0;
    hst[n1 + 64][u] = (f16)hv1;
    __syncthreads();
    if (tid < 128) {
        union { v8f16 v; unsigned long long q[2]; } c;
        c.v = *(const v8f16*)&hst[tid][0];
        unsigned long long* gp = (unsigned long long*)(slotbase + ((size_t)tid << 10) + (s << 3));
        __hip_atomic_store(gp,     c.q[0], __ATOMIC_RELAXED, __HIP_MEMORY_SCOPE_AGENT);
        __hip_atomic_store(gp + 1, c.q[1], __ATOMIC_RELAXED, __HIP_MEMORY_SCOPE_AGENT);
    }
}

template<bool XF16>
__global__ void __launch_bounds__(512)
lstm_main(const float* __restrict__ x, const f16* __restrict__ xf,
          const f16* __restrict__ wsW, const float* __restrict__ wsB,
          f16* __restrict__ hseq, const float* __restrict__ c0,
          float* __restrict__ out, unsigned* __restrict__ bar)
{
    __shared__ f16   wlds[32][2056];   // 131584 B
    __shared__ float glds[128][36];    //  18432 B (2-way max conflicts)
    __shared__ f16   hst[128][8];      //   2048 B h-store staging

    const int tid   = threadIdx.x;
    const int wgid  = blockIdx.x;
    const int layer = wgid >> 7;
    const int s     = wgid & 127;
    const int lane  = tid & 63;
    const int wave  = tid >> 6;
    const int quad  = lane >> 4;
    const int l15   = lane & 15;
    const int rb    = wave & 3;        // rows [32rb, 32rb+32)
    const int ks    = wave >> 2;       // K-split (512-half slices per phase)

    for (int idx = tid; idx < 8192; idx += 512) {
        int cc = idx >> 8;
        int k8 = (idx & 255) << 3;
        int col = ((cc >> 3) << 10) + (s << 3) + (cc & 7);
        *(v8f16*)(&wlds[cc][k8]) =
            *(const v8f16*)(wsW + (((size_t)(layer*4096 + col)) << 11) + k8);
    }

    const int u  = tid & 7;
    const int jg = (s << 3) + u;
    const float bi = wsB[layer*4096 +        jg];
    const float bf = wsB[layer*4096 + 1024 + jg];
    const float bg = wsB[layer*4096 + 2048 + jg];
    const float bo = wsB[layer*4096 + 3072 + jg];
    const int n1 = tid >> 3;
    float cr0 = c0[((size_t)layer << 17) + ((size_t)n1 << 10) + jg];
    float cr1 = c0[((size_t)layer << 17) + ((size_t)(n1 + 64) << 10) + jg];

    __syncthreads();

    const int kq   = quad << 3;
    const int row0 = (rb << 5) + l15;
    const int kslc = ks << 9;                       // 512-half K-slice offset
    const int arow = (row0 << 10) + kslc + kq;

    f16* h0b = hseq;
    f16* h1b = hseq + HS_BANK;
    unsigned* f0 = bar;             // layer-0 flags: f0[s*4] = last finished step+1
    unsigned* f1 = bar + 512;       // layer-1 flags (u32 units; 16-B stride)

    v8f16 A0[CHUNK], A1[CHUNK], C0[CHUNK], C1[CHUNK];

    if (layer == 0) {
        for (int t = 0; t < TSTEPS; ++t) {
            v4f32 acc[2][2] = {};

            // ---- independent phase: x[t] @ Wih (before the flag!) ----
            if (XF16) {
                const f16* p0 = xf + ((size_t)t << 17) + arow;
                const f16* p1 = p0 + (16 << 10);
                load_chunk(p0, p1, 0,   A0, A1);
                load_chunk(p0, p1, 256, C0, C1);
                mfma_chunk(A0, A1, wlds, l15, kq, kslc,       acc);
                mfma_chunk(C0, C1, wlds, l15, kq, kslc + 256, acc);
            } else {
                const float* p0 = x + ((size_t)t << 17) + arow;
                const float* p1 = p0 + (16 << 10);
                #pragma unroll
                for (int k = 0; k < 512; k += 32) {
                    v4f32 w0 = *(const v4f32*)(p0 + k), w1 = *(const v4f32*)(p0 + k + 4);
                    v4f32 y0 = *(const v4f32*)(p1 + k), y1 = *(const v4f32*)(p1 + k + 4);
                    v8f16 a0 = cvt8(w0, w1);
                    v8f16 a1 = cvt8(y0, y1);
                    v8f16 b0 = *(const v8f16*)(&wlds[l15     ][kslc + k + kq]);
                    v8f16 b1 = *(const v8f16*)(&wlds[16 + l15][kslc + k + kq]);
                    acc[0][0] = __builtin_amdgcn_mfma_f32_16x16x32_f16(a0, b0, acc[0][0], 0, 0, 0);
                    acc[0][1] = __builtin_amdgcn_mfma_f32_16x16x32_f16(a0, b1, acc[0][1], 0, 0, 0);
                    acc[1][0] = __builtin_amdgcn_mfma_f32_16x16x32_f16(a1, b0, acc[1][0], 0, 0, 0);
                    acc[1][1] = __builtin_amdgcn_mfma_f32_16x16x32_f16(a1, b1, acc[1][1], 0, 0, 0);
                }
            }

            // ---- wait: all 128 layer-0 WGs finished step t-1 (parallel poll) ----
            if (t > 0) {
                if (tid < 128) {
                    const unsigned* fp = f0 + (tid << 2);
                    unsigned need = (unsigned)t;
                    while (ld_cnt(fp) < need) __builtin_amdgcn_s_sleep(1);
                }
                __syncthreads();
            }

            // ---- dependent phase: h[t] @ Whh, register-preloaded ----
            if (XF16) {
                const f16* p0 = h0b + (size_t)t * SLOT + arow;
                const f16* p1 = p0 + (16 << 10);
                load_chunk(p0, p1, 0,   A0, A1);
                load_chunk(p0, p1, 256, C0, C1);
                mfma_chunk(A0, A1, wlds, l15, kq, 1024 + kslc,       acc);
                mfma_chunk(C0, C1, wlds, l15, kq, 1024 + kslc + 256, acc);
            } else {
                const f16* p0 = h0b + (size_t)t * SLOT + arow;
                kloop16(p0, p0 + (16 << 10), wlds, l15, kq, 1024 + kslc, acc);
            }

            reduce_splits(acc, glds, rb, quad, l15, ks);

            float hv0, hv1;
            cell2(glds, n1, u, bi, bf, bg, bo, cr0, cr1, hv0, hv1);
            store_h_slot(hst, h0b + (size_t)(t + 1) * SLOT, s, tid, n1, u, hv0, hv1);

            __syncthreads();   // drains the 16-B agent stores (vmcnt) per wave
            if (tid == 0)
                __hip_atomic_store(f0 + (s << 2), (unsigned)(t + 1),
                                   __ATOMIC_RELAXED, __HIP_MEMORY_SCOPE_AGENT);
        }
    } else {
        for (int t = 0; t < TSTEPS; ++t) {
            // wait: own recurrence h1[t] (f1 >= t) and input h0-out[t] (f0 >= t+1)
            if (tid < 128) {
                if (t > 0) {
                    const unsigned* fp = f1 + (tid << 2);
                    unsigned need = (unsigned)t;
                    while (ld_cnt(fp) < need) __builtin_amdgcn_s_sleep(1);
                }
            } else if (tid < 256) {
                const unsigned* fp = f0 + ((tid - 128) << 2);
                unsigned need = (unsigned)(t + 1);
                while (ld_cnt(fp) < need) __builtin_amdgcn_s_sleep(1);
            }
            __syncthreads();

            v4f32 acc[2][2] = {};
            // two dependent phases, chunk-interleaved so loads stay in flight
            const f16* p0 = h1b + (size_t)t * SLOT + arow;         // own recurrence
            const f16* p1 = p0 + (16 << 10);
            const f16* q0 = h0b + (size_t)(t + 1) * SLOT + arow;   // layer-0 output, step t
            const f16* q1 = q0 + (16 << 10);

            load_chunk(p0, p1, 0,   A0, A1);
            load_chunk(p0, p1, 256, C0, C1);
            mfma_chunk(A0, A1, wlds, l15, kq, 1024 + kslc,       acc);
            load_chunk(q0, q1, 0,   A0, A1);
            mfma_chunk(C0, C1, wlds, l15, kq, 1024 + kslc + 256, acc);
            load_chunk(q0, q1, 256, C0, C1);
            mfma_chunk(A0, A1, wlds, l15, kq, kslc,       acc);
            mfma_chunk(C0, C1, wlds, l15, kq, kslc + 256, acc);

            reduce_splits(acc, glds, rb, quad, l15, ks);

            float hv0, hv1;
            cell2(glds, n1, u, bi, bf, bg, bo, cr0, cr1, hv0, hv1);
            if (t < TSTEPS - 1) {
                store_h_slot(hst, h1b + (size_t)(t + 1) * SLOT, s, tid, n1, u, hv0, hv1);
                __syncthreads();
                if (tid == 0)
                    __hip_atomic_store(f1 + (s << 2), (unsigned)(t + 1),
                                       __ATOMIC_RELAXED, __HIP_MEMORY_SCOPE_AGENT);
            } else {
                out[(n1 << 10) + jg] = hv0;
                out[((n1 + 64) << 10) + jg] = hv1;
            }
        }
    }
}

extern "C" void kernel_launch(void* const* d_in, const int* in_sizes, int n_in,
                              void* d_out, int out_size, void* d_ws, size_t ws_size,
                              hipStream_t stream) {
    const float* x   = (const float*)d_in[0];
    const float* h0  = (const float*)d_in[1];
    const float* c0  = (const float*)d_in[2];
    const float* Wih = (const float*)d_in[3];
    const float* Whh = (const float*)d_in[4];
    const float* bih = (const float*)d_in[5];
    const float* bhh = (const float*)d_in[6];
    float* out = (float*)d_out;

    char* ws = (char*)d_ws;
    const bool xf16 = (ws_size >= NEED2);

    f16*      wsW  = (f16*)ws;
    float*    wsB  = (float*)(ws + SZ_W);
    f16*      hseq = (f16*)(ws + SZ_W + SZ_B);
    unsigned* bar  = (unsigned*)(ws + SZ_W + SZ_B + SZ_HSEQ);
    f16*      xf   = (f16*)(ws + NEED1);
    int do_xf = xf16 ? 1 : 0;

    lstm_init<<<2048, 256, 0, stream>>>(x, h0, Wih, Whh, bih, bhh,
                                        wsW, wsB, hseq, bar, xf, do_xf);

    void* kargs[] = { (void*)&x, (void*)&xf, (void*)&wsW, (void*)&wsB,
                      (void*)&hseq, (void*)&c0, (void*)&out, (void*)&bar };
    if (xf16) {
        hipLaunchCooperativeKernel((void*)&lstm_main<true>, dim3(256), dim3(512), kargs, 0, stream);
    } else {
        hipLaunchCooperativeKernel((void*)&lstm_main<false>, dim3(256), dim3(512), kargs, 0, stream);
    }
}

// Round 2
// 3294.048 us; speedup vs baseline: 1.5507x; 1.4673x over previous
//
#include <hip/hip_runtime.h>

// LSTM T=256, N=128, D=H=1024, L=2.  Persistent cooperative kernel, 256 WGs x 512.
// WG (layer l, slice s) owns hidden units [8s,8s+8) => 32 gate cols, weights in LDS.
// Round-6 changes vs round-5 (evidence: VGPR stuck at 88 => preload was sunk;
// WRITE_SIZE 525MB vs 132MB produced => 4x partial-sector write amplification;
// FETCH 1.03GB ~= h readback => consumers miss LLC and pay HBM latency):
//  (1) s-major h-slot layout [s][n][u]: producer WG s writes 2KB CONTIGUOUS
//      (full 64-B sectors, fast drain); consumer 16-B fragments (8 consecutive
//      hidden units of one batch row) stay contiguous, and a wave's 16 lanes
//      read a contiguous 256-512B block (4x fewer lines).
//  (2) sched_barrier(0) between the 32-load block and the MFMA block forces the
//      whole A-tile into flight (one LLC/HBM latency instead of ~5).
//  (3) layer-1: own-recurrence loads (critical) batched first; layer-0-output
//      loads (ready early, L2-warm) issued between P-chunk MFMAs.
// Flags: per-WG 16-B-strided words, relaxed agent store / parallel poll.

typedef _Float16 f16;
typedef f16  v8f16 __attribute__((ext_vector_type(8)));
typedef float v4f32 __attribute__((ext_vector_type(4)));

#define TSTEPS 256
#define SLOT   131072u
static constexpr size_t HS_BANK = (size_t)258 * SLOT;   // elems per layer bank

#define SZ_W     ((size_t)2*4096*2048*2)   /* fp16 weights [l][col][k2048] */
#define SZ_B     ((size_t)2*4096*4)        /* fused bias fp32 */
#define SZ_HSEQ  ((size_t)2*258*SLOT*2)    /* h slots, 2 banks, fp16 */
#define SZ_BAR   ((size_t)4096)            /* 2 layers x 128 flags x 16 B */
#define SZ_XF    ((size_t)256*128*1024*2)  /* x in fp16 */
#define NEED1    (SZ_W + SZ_B + SZ_HSEQ + SZ_BAR)
#define NEED2    (NEED1 + SZ_XF)

__global__ void lstm_init(const float* __restrict__ x,
                          const float* __restrict__ h0,
                          const float* __restrict__ Wih, const float* __restrict__ Whh,
                          const float* __restrict__ bih, const float* __restrict__ bhh,
                          f16* __restrict__ wsW, float* __restrict__ wsB,
                          f16* __restrict__ hseq, unsigned* __restrict__ bar,
                          f16* __restrict__ xf, int do_xf)
{
    size_t tid  = (size_t)blockIdx.x * blockDim.x + threadIdx.x;
    size_t nthr = (size_t)gridDim.x * blockDim.x;
    // weights: [l][col][k], k<1024 -> W_ih, k>=1024 -> W_hh
    for (size_t i = tid; i < 16777216u; i += nthr) {
        unsigned l = (unsigned)(i >> 23), rem = (unsigned)(i & 8388607u);
        unsigned col = rem >> 11, k = rem & 2047u;
        float v = (k < 1024u) ? Wih[(size_t)l*4194304u + (size_t)col*1024u + k]
                              : Whh[(size_t)l*4194304u + (size_t)col*1024u + (k-1024u)];
        wsW[i] = (f16)v;
    }
    for (size_t i = tid; i < 8192u; i += nthr) wsB[i] = bih[i] + bhh[i];
    // initial h slots in s-major layout: (n,k) -> (k>>3)*1024 + n*8 + (k&7)
    for (size_t i = tid; i < 131072u; i += nthr) {
        unsigned n = (unsigned)(i >> 10), k = (unsigned)(i & 1023u);
        unsigned dst = ((k >> 3) << 10) + (n << 3) + (k & 7u);
        hseq[dst]           = (f16)h0[i];             // layer0 slot 0
        hseq[HS_BANK + dst] = (f16)h0[131072u + i];   // layer1 slot 0
    }
    for (size_t i = tid; i < 1024u; i += nthr) bar[i] = 0u;   // all flags
    if (do_xf) {
        for (size_t i = tid; i < 33554432u; i += nthr) xf[i] = (f16)x[i];
    }
}

__device__ __forceinline__ float sigmoid_fast(float v) { return 1.0f / (1.0f + __expf(-v)); }
__device__ __forceinline__ float tanh_fast(float v)    { return 1.0f - 2.0f / (__expf(2.0f*v) + 1.0f); }

__device__ __forceinline__ v8f16 cvt8(v4f32 lo, v4f32 hi) {
    v8f16 r;
    r[0]=(f16)lo[0]; r[1]=(f16)lo[1]; r[2]=(f16)lo[2]; r[3]=(f16)lo[3];
    r[4]=(f16)hi[0]; r[5]=(f16)hi[1]; r[6]=(f16)hi[2]; r[7]=(f16)hi[3];
    return r;
}

__device__ __forceinline__ unsigned ld_cnt(const unsigned* p) {
    return __hip_atomic_load(p, __ATOMIC_RELAXED, __HIP_MEMORY_SCOPE_AGENT);
}

#define CHUNK 8

// row-major source (xf): rows stride 1024 halves, a1 = rows +16
__device__ __forceinline__ void load_row(const f16* p, int off,
                                         v8f16 a0[CHUNK], v8f16 a1[CHUNK])
{
    #pragma unroll
    for (int i = 0; i < CHUNK; ++i) {
        a0[i] = *(const v8f16*)(p + off + 32*i);
        a1[i] = *(const v8f16*)(p + off + 16384 + 32*i);
    }
}

// s-major h slot: element (n,k) at (k>>3)*1024 + n*8 + (k&7)
// p = slot + ((kslc+kq)>>3)*1024 + row0*8 ; per k-iter stride 4*1024 halves
__device__ __forceinline__ void load_sm(const f16* p, int off,
                                        v8f16 a0[CHUNK], v8f16 a1[CHUNK])
{
    #pragma unroll
    for (int i = 0; i < CHUNK; ++i) {
        a0[i] = *(const v8f16*)(p + off + 4096*i);
        a1[i] = *(const v8f16*)(p + off + 128 + 4096*i);   // rows +16 -> +128 halves
    }
}

// consume one 8-iteration chunk (B from LDS weights)
__device__ __forceinline__ void mfma_chunk(const v8f16 a0[CHUNK], const v8f16 a1[CHUNK],
                                           const f16 (*wl)[2056], int l15, int kq, int kbase,
                                           v4f32 acc[2][2])
{
    #pragma unroll
    for (int i = 0; i < CHUNK; ++i) {
        int k = kbase + 32*i;
        v8f16 b0 = *(const v8f16*)(&wl[l15     ][k + kq]);
        v8f16 b1 = *(const v8f16*)(&wl[16 + l15][k + kq]);
        acc[0][0] = __builtin_amdgcn_mfma_f32_16x16x32_f16(a0[i], b0, acc[0][0], 0, 0, 0);
        acc[0][1] = __builtin_amdgcn_mfma_f32_16x16x32_f16(a0[i], b1, acc[0][1], 0, 0, 0);
        acc[1][0] = __builtin_amdgcn_mfma_f32_16x16x32_f16(a1[i], b0, acc[1][0], 0, 0, 0);
        acc[1][1] = __builtin_amdgcn_mfma_f32_16x16x32_f16(a1[i], b1, acc[1][1], 0, 0, 0);
    }
}

__device__ __forceinline__ void reduce_splits(v4f32 acc[2][2], float (*gl)[36],
                                              int rb, int quad, int l15, int ks)
{
    if (ks == 0) {
        #pragma unroll
        for (int mt = 0; mt < 2; ++mt) {
            int rrow = (rb << 5) + (mt << 4) + (quad << 2);
            #pragma unroll
            for (int r = 0; r < 4; ++r) {
                gl[rrow + r][l15     ] = acc[mt][0][r];
                gl[rrow + r][16 + l15] = acc[mt][1][r];
            }
        }
    }
    __syncthreads();
    if (ks == 1) {
        #pragma unroll
        for (int mt = 0; mt < 2; ++mt) {
            int rrow = (rb << 5) + (mt << 4) + (quad << 2);
            #pragma unroll
            for (int r = 0; r < 4; ++r) {
                gl[rrow + r][l15     ] += acc[mt][0][r];
                gl[rrow + r][16 + l15] += acc[mt][1][r];
            }
        }
    }
    __syncthreads();
}

__device__ __forceinline__ void cell2(const float (*gl)[36], int n1, int u,
                                      float bi, float bf, float bg, float bo,
                                      float& cr0, float& cr1, float& h0o, float& h1o)
{
    {
        float gi = gl[n1][u]      + bi;
        float gf = gl[n1][8 + u]  + bf;
        float gg = gl[n1][16 + u] + bg;
        float go = gl[n1][24 + u] + bo;
        float cn = sigmoid_fast(gf) * cr0 + sigmoid_fast(gi) * tanh_fast(gg);
        cr0 = cn;
        h0o = sigmoid_fast(go) * tanh_fast(cn);
    }
    {
        int n = n1 + 64;
        float gi = gl[n][u]      + bi;
        float gf = gl[n][8 + u]  + bf;
        float gg = gl[n][16 + u] + bg;
        float go = gl[n][24 + u] + bo;
        float cn = sigmoid_fast(gf) * cr1 + sigmoid_fast(gi) * tanh_fast(gg);
        cr1 = cn;
        h1o = sigmoid_fast(go) * tanh_fast(cn);
    }
}

// stage hv in LDS, then 128 threads store the WG's CONTIGUOUS 2 KB region:
// slot element (n, 8s+u) lives at s*1024 + n*8 + u
__device__ __forceinline__ void store_h_slot(f16 (*hst)[8], f16* slotbase, int s,
                                             int tid, int n1, int u,
                                             float hv0, float hv1)
{
    hst[n1     ][u] = (f16)hv0;
    hst[n1 + 64][u] = (f16)hv1;
    __syncthreads();
    if (tid < 128) {
        union { v8f16 v; unsigned long long q[2]; } c;
        c.v = *(const v8f16*)&hst[tid][0];
        unsigned long long* gp = (unsigned long long*)(slotbase + ((size_t)s << 10) + (tid << 3));
        __hip_atomic_store(gp,     c.q[0], __ATOMIC_RELAXED, __HIP_MEMORY_SCOPE_AGENT);
        __hip_atomic_store(gp + 1, c.q[1], __ATOMIC_RELAXED, __HIP_MEMORY_SCOPE_AGENT);
    }
}

template<bool XF16>
__global__ void __launch_bounds__(512)
lstm_main(const float* __restrict__ x, const f16* __restrict__ xf,
          const f16* __restrict__ wsW, const float* __restrict__ wsB,
          f16* __restrict__ hseq, const float* __restrict__ c0,
          float* __restrict__ out, unsigned* __restrict__ bar)
{
    __shared__ f16   wlds[32][2056];   // 131584 B
    __shared__ float glds[128][36];    //  18432 B (2-way max conflicts)
    __shared__ f16   hst[128][8];      //   2048 B h-store staging

    const int tid   = threadIdx.x;
    const int wgid  = blockIdx.x;
    const int layer = wgid >> 7;
    const int s     = wgid & 127;
    const int lane  = tid & 63;
    const int wave  = tid >> 6;
    const int quad  = lane >> 4;
    const int l15   = lane & 15;
    const int rb    = wave & 3;        // rows [32rb, 32rb+32)
    const int ks    = wave >> 2;       // K-split (512-half slices per phase)

    for (int idx = tid; idx < 8192; idx += 512) {
        int cc = idx >> 8;
        int k8 = (idx & 255) << 3;
        int col = ((cc >> 3) << 10) + (s << 3) + (cc & 7);
        *(v8f16*)(&wlds[cc][k8]) =
            *(const v8f16*)(wsW + (((size_t)(layer*4096 + col)) << 11) + k8);
    }

    const int u  = tid & 7;
    const int jg = (s << 3) + u;
    const float bi = wsB[layer*4096 +        jg];
    const float bf = wsB[layer*4096 + 1024 + jg];
    const float bg = wsB[layer*4096 + 2048 + jg];
    const float bo = wsB[layer*4096 + 3072 + jg];
    const int n1 = tid >> 3;
    float cr0 = c0[((size_t)layer << 17) + ((size_t)n1 << 10) + jg];
    float cr1 = c0[((size_t)layer << 17) + ((size_t)(n1 + 64) << 10) + jg];

    __syncthreads();

    const int kq   = quad << 3;
    const int row0 = (rb << 5) + l15;
    const int kslc = ks << 9;                       // 512-half K-slice offset
    const int arow = (row0 << 10) + kslc + kq;      // row-major (xf) A offset
    const int jrow = (((kslc + kq) >> 3) << 10) + (row0 << 3);  // s-major A offset

    f16* h0b = hseq;
    f16* h1b = hseq + HS_BANK;
    unsigned* f0 = bar;             // layer-0 flags: f0[s*4] = last finished step+1
    unsigned* f1 = bar + 512;       // layer-1 flags (u32 units; 16-B stride)

    v8f16 A0[CHUNK], A1[CHUNK], C0[CHUNK], C1[CHUNK];

    if (layer == 0) {
        for (int t = 0; t < TSTEPS; ++t) {
            v4f32 acc[2][2] = {};

            // ---- independent phase: x[t] @ Wih (before the flag!) ----
            if (XF16) {
                const f16* xp = xf + ((size_t)t << 17) + arow;
                load_row(xp, 0,   A0, A1);
                load_row(xp, 256, C0, C1);
                __builtin_amdgcn_sched_barrier(0);
                mfma_chunk(A0, A1, wlds, l15, kq, kslc,       acc);
                mfma_chunk(C0, C1, wlds, l15, kq, kslc + 256, acc);
            } else {
                const float* p0 = x + ((size_t)t << 17) + arow;
                const float* p1 = p0 + (16 << 10);
                #pragma unroll
                for (int k = 0; k < 512; k += 32) {
                    v4f32 w0 = *(const v4f32*)(p0 + k), w1 = *(const v4f32*)(p0 + k + 4);
                    v4f32 y0 = *(const v4f32*)(p1 + k), y1 = *(const v4f32*)(p1 + k + 4);
                    v8f16 a0 = cvt8(w0, w1);
                    v8f16 a1 = cvt8(y0, y1);
                    v8f16 b0 = *(const v8f16*)(&wlds[l15     ][kslc + k + kq]);
                    v8f16 b1 = *(const v8f16*)(&wlds[16 + l15][kslc + k + kq]);
                    acc[0][0] = __builtin_amdgcn_mfma_f32_16x16x32_f16(a0, b0, acc[0][0], 0, 0, 0);
                    acc[0][1] = __builtin_amdgcn_mfma_f32_16x16x32_f16(a0, b1, acc[0][1], 0, 0, 0);
                    acc[1][0] = __builtin_amdgcn_mfma_f32_16x16x32_f16(a1, b0, acc[1][0], 0, 0, 0);
                    acc[1][1] = __builtin_amdgcn_mfma_f32_16x16x32_f16(a1, b1, acc[1][1], 0, 0, 0);
                }
            }

            // ---- wait: all 128 layer-0 WGs finished step t-1 (parallel poll) ----
            if (t > 0) {
                if (tid < 128) {
                    const unsigned* fp = f0 + (tid << 2);
                    unsigned need = (unsigned)t;
                    while (ld_cnt(fp) < need) __builtin_amdgcn_s_sleep(1);
                }
                __syncthreads();
            }

            // ---- dependent phase: h[t] @ Whh, fully batched loads ----
            {
                const f16* hp = h0b + (size_t)t * SLOT + jrow;
                load_sm(hp, 0,     A0, A1);
                load_sm(hp, 32768, C0, C1);
                __builtin_amdgcn_sched_barrier(0);
                mfma_chunk(A0, A1, wlds, l15, kq, 1024 + kslc,       acc);
                mfma_chunk(C0, C1, wlds, l15, kq, 1024 + kslc + 256, acc);
            }

            reduce_splits(acc, glds, rb, quad, l15, ks);

            float hv0, hv1;
            cell2(glds, n1, u, bi, bf, bg, bo, cr0, cr1, hv0, hv1);
            store_h_slot(hst, h0b + (size_t)(t + 1) * SLOT, s, tid, n1, u, hv0, hv1);

            __syncthreads();   // drains the agent stores (vmcnt) per wave
            if (tid == 0)
                __hip_atomic_store(f0 + (s << 2), (unsigned)(t + 1),
                                   __ATOMIC_RELAXED, __HIP_MEMORY_SCOPE_AGENT);
        }
    } else {
        v8f16 D0[CHUNK], D1[CHUNK];
        for (int t = 0; t < TSTEPS; ++t) {
            // wait: own recurrence h1[t] (f1 >= t) and input h0-out[t] (f0 >= t+1)
            if (tid < 128) {
                if (t > 0) {
                    const unsigned* fp = f1 + (tid << 2);
                    unsigned need = (unsigned)t;
                    while (ld_cnt(fp) < need) __builtin_amdgcn_s_sleep(1);
                }
            } else if (tid < 256) {
                const unsigned* fp = f0 + ((tid - 128) << 2);
                unsigned need = (unsigned)(t + 1);
                while (ld_cnt(fp) < need) __builtin_amdgcn_s_sleep(1);
            }
            __syncthreads();

            v4f32 acc[2][2] = {};
            const f16* pp = h1b + (size_t)t * SLOT + jrow;         // own recurrence (critical)
            const f16* qp = h0b + (size_t)(t + 1) * SLOT + jrow;   // layer-0 out (L2-warm)

            load_sm(pp, 0,     A0, A1);        // P batch: 32 loads in flight
            load_sm(pp, 32768, C0, C1);
            __builtin_amdgcn_sched_barrier(0);
            mfma_chunk(A0, A1, wlds, l15, kq, 1024 + kslc,       acc);
            load_sm(qp, 0,     D0, D1);        // Q overlaps P MFMAs
            mfma_chunk(C0, C1, wlds, l15, kq, 1024 + kslc + 256, acc);
            load_sm(qp, 32768, A0, A1);        // reuse P-A regs (already consumed)
            mfma_chunk(D0, D1, wlds, l15, kq, kslc,       acc);
            mfma_chunk(A0, A1, wlds, l15, kq, kslc + 256, acc);

            reduce_splits(acc, glds, rb, quad, l15, ks);

            float hv0, hv1;
            cell2(glds, n1, u, bi, bf, bg, bo, cr0, cr1, hv0, hv1);
            if (t < TSTEPS - 1) {
                store_h_slot(hst, h1b + (size_t)(t + 1) * SLOT, s, tid, n1, u, hv0, hv1);
                __syncthreads();
                if (tid == 0)
                    __hip_atomic_store(f1 + (s << 2), (unsigned)(t + 1),
                                       __ATOMIC_RELAXED, __HIP_MEMORY_SCOPE_AGENT);
            } else {
                out[(n1 << 10) + jg] = hv0;
                out[((n1 + 64) << 10) + jg] = hv1;
            }
        }
    }
}

extern "C" void kernel_launch(void* const* d_in, const int* in_sizes, int n_in,
                              void* d_out, int out_size, void* d_ws, size_t ws_size,
                              hipStream_t stream) {
    const float* x   = (const float*)d_in[0];
    const float* h0  = (const float*)d_in[1];
    const float* c0  = (const float*)d_in[2];
    const float* Wih = (const float*)d_in[3];
    const float* Whh = (const float*)d_in[4];
    const float* bih = (const float*)d_in[5];
    const float* bhh = (const float*)d_in[6];
    float* out = (float*)d_out;

    char* ws = (char*)d_ws;
    const bool xf16 = (ws_size >= NEED2);

    f16*      wsW  = (f16*)ws;
    float*    wsB  = (float*)(ws + SZ_W);
    f16*      hseq = (f16*)(ws + SZ_W + SZ_B);
    unsigned* bar  = (unsigned*)(ws + SZ_W + SZ_B + SZ_HSEQ);
    f16*      xf   = (f16*)(ws + NEED1);
    int do_xf = xf16 ? 1 : 0;

    lstm_init<<<2048, 256, 0, stream>>>(x, h0, Wih, Whh, bih, bhh,
                                        wsW, wsB, hseq, bar, xf, do_xf);

    void* kargs[] = { (void*)&x, (void*)&xf, (void*)&wsW, (void*)&wsB,
                      (void*)&hseq, (void*)&c0, (void*)&out, (void*)&bar };
    if (xf16) {
        hipLaunchCooperativeKernel((void*)&lstm_main<true>, dim3(256), dim3(512), kargs, 0, stream);
    } else {
        hipLaunchCooperativeKernel((void*)&lstm_main<false>, dim3(256), dim3(512), kargs, 0, stream);
    }
}